// Round 8
// baseline (108.504 us; speedup 1.0000x reference)
//
#include <hip/hip_runtime.h>
#include <math.h>

#define J 5
#define LOG2E 1.4426950408889634f
#define LN2   0.6931471805599453f

// LUT config: phase-2 is {o, o', o''}(s), cubic Hermite per segment.
#define NSEG   128
#define SMAX   16.0f
#define SEG_STRIDE 12                    // floats per segment (3 x float4)
#define LUT_FLOATS (NSEG * SEG_STRIDE)   // 1536 floats = 6 KB
#define CONST_BASE LUT_FLOATS            // phase-1 constants start here

typedef float v2f __attribute__((ext_vector_type(2)));

#if defined(__HIP_DEVICE_COMPILE__) && __has_builtin(__builtin_amdgcn_rcpf)
__device__ __forceinline__ float fastrcp(float x) { return __builtin_amdgcn_rcpf(x); }
#else
__device__ __forceinline__ float fastrcp(float x) { return 1.0f / x; }
#endif

#if defined(__HIP_DEVICE_COMPILE__) && __has_builtin(__builtin_amdgcn_rsqf)
__device__ __forceinline__ float fastrsq(float x) { return __builtin_amdgcn_rsqf(x); }
#else
__device__ __forceinline__ float fastrsq(float x) { return 1.0f / sqrtf(x); }
#endif

#if defined(__HIP_DEVICE_COMPILE__) && __has_builtin(__builtin_amdgcn_exp2f)
__device__ __forceinline__ float fexp2(float x) { return __builtin_amdgcn_exp2f(x); }
#else
__device__ __forceinline__ float fexp2(float x) { return exp2f(x); }
#endif

// ---- packed helpers ----
__device__ __forceinline__ v2f v2s(float a) { return (v2f){a, a}; }
__device__ __forceinline__ v2f vfma(v2f a, v2f b, v2f c) { return __builtin_elementwise_fma(a, b, c); }
__device__ __forceinline__ v2f vfma(v2f a, float b, v2f c) { return __builtin_elementwise_fma(a, v2s(b), c); }
__device__ __forceinline__ v2f v2exp2(v2f x) { return (v2f){fexp2(x.x), fexp2(x.y)}; }
__device__ __forceinline__ v2f v2rcp (v2f x) { return (v2f){fastrcp(x.x), fastrcp(x.y)}; }
__device__ __forceinline__ v2f v2rsq (v2f x) { return (v2f){fastrsq(x.x), fastrsq(x.y)}; }

// ---------------- setup: build phase-1 constants + phase-2 Hermite LUT ----------------
__device__ void node_eval(float s, const float* r1, const float* c1,
                          const float* W2, const float* b2, const float* wo, float bo,
                          float& o, float& o1, float& o2, float& o3)
{
    float h[J], h1[J], h2[J], h3[J];
#pragma unroll
    for (int j = 0; j < J; ++j) {
        const float a  = fmaf(r1[j], s, c1[j]);
        const float e  = __expf(-fabsf(a));
        const float w  = fastrcp(1.0f + e);
        const float sg = (a >= 0.0f) ? w : 1.0f - w;
        const float sp = fmaxf(a, 0.0f) + __logf(1.0f + e);
        const float d1 = sg * (1.0f - sg);
        const float d2 = d1 * (1.0f - 2.0f * sg);
        const float r  = r1[j];
        h[j]  = sp;
        h1[j] = sg * r;
        h2[j] = d1 * r * r;
        h3[j] = d2 * r * r * r;
    }
    o = bo; o1 = 0.0f; o2 = 0.0f; o3 = 0.0f;
#pragma unroll
    for (int i = 0; i < J; ++i) {
        float g = b2[i], G1 = 0.0f, G2 = 0.0f, G3 = 0.0f;
#pragma unroll
        for (int j = 0; j < J; ++j) {
            const float w = W2[i * J + j];
            g  = fmaf(w, h[j],  g);
            G1 = fmaf(w, h1[j], G1);
            G2 = fmaf(w, h2[j], G2);
            G3 = fmaf(w, h3[j], G3);
        }
        const float e  = __expf(-fabsf(g));
        const float w  = fastrcp(1.0f + e);
        const float sg = (g >= 0.0f) ? w : 1.0f - w;
        const float sp = fmaxf(g, 0.0f) + __logf(1.0f + e);
        const float d1 = sg * (1.0f - sg);
        const float d2 = d1 * (1.0f - 2.0f * sg);
        o  = fmaf(wo[i], sp, o);
        o1 = fmaf(wo[i], sg * G1, o1);
        o2 = fmaf(wo[i], fmaf(d1, G1 * G1, sg * G2), o2);
        o3 = fmaf(wo[i], fmaf(d2 * G1, G1 * G1, fmaf(3.0f * d1, G1 * G2, sg * G3)), o3);
    }
}

__global__ void setup_kernel(const float* __restrict__ w_logm, const float* __restrict__ b_logm,
                             const float* __restrict__ w_ttm,  const float* __restrict__ b_ttm,
                             const float* __restrict__ w_exp,  const float* __restrict__ b_exp,
                             const float* __restrict__ W1,     const float* __restrict__ b1,
                             const float* __restrict__ W2,     const float* __restrict__ b2,
                             const float* __restrict__ Wo,     const float* __restrict__ bo,
                             float* __restrict__ c)
{
    const int k = threadIdx.x;           // 0..NSEG-1, one per LUT segment

    if (k < J) {
        const float ewl = __expf(w_logm[k]);
        const float ewt = __expf(w_ttm[k]);
        const float ewe = __expf(w_exp[k]);
        c[CONST_BASE + 0  + k] = ewl * LOG2E;
        c[CONST_BASE + 5  + k] = b_logm[k] * LOG2E;
        c[CONST_BASE + 10 + k] = ewl;
        c[CONST_BASE + 15 + k] = -ewt * LOG2E;
        c[CONST_BASE + 20 + k] = -b_ttm[k] * LOG2E;
        c[CONST_BASE + 25 + k] = ewe;
        c[CONST_BASE + 30 + k] = ewt * ewe;
        c[CONST_BASE + 35 + k] = 0.5f * ewl;           // half_ewl
        c[CONST_BASE + 40 + k] = 0.25f * ewl * ewl;    // quarter_e2
    }

    float r1[J], c1[J], b2r[J], wor[J], W2r[J * J];
#pragma unroll
    for (int i = 0; i < J; ++i) {
        float r = 0.0f, cc = b1[i];
#pragma unroll
        for (int j = 0; j < J; ++j) {
            const float w = W1[i * J + j];
            r += w;
            cc = fmaf(w, b_exp[j], cc);
        }
        r1[i] = r; c1[i] = cc;
        b2r[i] = b2[i]; wor[i] = Wo[i];
    }
#pragma unroll
    for (int t = 0; t < J * J; ++t) W2r[t] = W2[t];
    const float bo0 = bo[0];

    const float h  = SMAX / (float)NSEG;
    const float s0 = h * (float)k;
    float Fa0, Fa1, Fa2, Fa3, Fb0, Fb1, Fb2, Fb3;
    node_eval(s0,     r1, c1, W2r, b2r, wor, bo0, Fa0, Fa1, Fa2, Fa3);
    node_eval(s0 + h, r1, c1, W2r, b2r, wor, bo0, Fb0, Fb1, Fb2, Fb3);

    float* seg = c + k * SEG_STRIDE;
    {   // F0 = o
        const float Da = h * Fa1, Db = h * Fb1, D = Fb0 - Fa0;
        seg[0] = Fa0; seg[1] = Da;
        seg[2] = 3.0f * D - 2.0f * Da - Db;
        seg[3] = -2.0f * D + Da + Db;
    }
    {   // F1 = o'
        const float Da = h * Fa2, Db = h * Fb2, D = Fb1 - Fa1;
        seg[4] = Fa1; seg[5] = Da;
        seg[6] = 3.0f * D - 2.0f * Da - Db;
        seg[7] = -2.0f * D + Da + Db;
    }
    {   // F2 = o''
        const float Da = h * Fa3, Db = h * Fb3, D = Fb2 - Fa2;
        seg[8]  = Fa2; seg[9]  = Da;
        seg[10] = 3.0f * D - 2.0f * Da - Db;
        seg[11] = -2.0f * D + Da + Db;
    }
}

// ---------------- main kernel ----------------
__device__ __forceinline__ void lut_eval(const float* __restrict__ lut, float s,
                                         float& F0, float& F1, float& F2)
{
    float t = s * ((float)NSEG / SMAX);
    t = fminf(fmaxf(t, 0.0f), (float)NSEG - 0.0005f);   // v_med3
    const float fl = floorf(t);
    const float fr = t - fl;
    const float* cp = lut + (int)fl * SEG_STRIDE;
    const float4 A = *(const float4*)(cp);
    const float4 B = *(const float4*)(cp + 4);
    const float4 C = *(const float4*)(cp + 8);
    F0 = fmaf(fmaf(fmaf(A.w, fr, A.z), fr, A.y), fr, A.x);
    F1 = fmaf(fmaf(fmaf(B.w, fr, B.z), fr, B.y), fr, B.x);
    F2 = fmaf(fmaf(fmaf(C.w, fr, C.z), fr, C.y), fr, C.x);
}

__global__ __launch_bounds__(256, 4) void smile_main(
    const float* __restrict__ ttm, const float* __restrict__ logm,
    const float* __restrict__ c, float* __restrict__ out, int n)
{
    __shared__ __align__(16) float lut[LUT_FLOATS];

    const int tid = blockIdx.x * blockDim.x + threadIdx.x;

    // ---- issue input loads FIRST so HBM latency overlaps the LDS fill ----
    float4 T4 = make_float4(0.f, 0.f, 0.f, 0.f);
    float4 L4 = make_float4(0.f, 0.f, 0.f, 0.f);
    const bool active = (tid * 4 < n);
    if (active) {
        T4 = ((const float4*)ttm)[tid];
        L4 = ((const float4*)logm)[tid];
    }

    // cooperative LDS fill: 1536 floats = 384 float4
    for (int t = threadIdx.x; t < LUT_FLOATS / 4; t += 256)
        ((float4*)lut)[t] = ((const float4*)c)[t];
    __syncthreads();

    if (!active) return;

    const v2f Ta = (v2f){T4.x, T4.y}, Tb = (v2f){T4.z, T4.w};
    const v2f La = (v2f){L4.x, L4.y}, Lb = (v2f){L4.z, L4.w};

    // ---- phase-1 constants (uniform -> SGPRs) ----
    const float* cb = c + CONST_BASE;
    float ewlb[J], blb[J], newtb[J], nbtb[J], ewe[J], wte[J], hewl[J], qe2[J];
#pragma unroll
    for (int j = 0; j < J; ++j) {
        ewlb[j]  = cb[0  + j];
        blb[j]   = cb[5  + j];
        newtb[j] = cb[15 + j];
        nbtb[j]  = cb[20 + j];
        ewe[j]   = cb[25 + j];
        wte[j]   = cb[30 + j];
        hewl[j]  = cb[35 + j];   // 0.5*ewl
        qe2[j]   = cb[40 + j];   // 0.25*ewl^2
    }

    // ============ phase 1: both packed chains interleaved in one loop ============
    v2f sa = v2s(0.0f), sLa = v2s(0.0f), sLLa = v2s(0.0f), sTa = v2s(0.0f);
    v2f sb = v2s(0.0f), sLb = v2s(0.0f), sLLb = v2s(0.0f), sTb = v2s(0.0f);
#pragma unroll
    for (int j = 0; j < J; ++j) {
        // --- independent front-ends (trans latency hidden across chains) ---
        const v2f x2A = vfma(La, ewlb[j], v2s(blb[j]));
        const v2f x2B = vfma(Lb, ewlb[j], v2s(blb[j]));
        const v2f exA = v2exp2(x2A);
        const v2f exB = v2exp2(x2B);
        const v2f zA  = vfma(Ta, newtb[j], v2s(nbtb[j]));
        const v2f zB  = vfma(Tb, newtb[j], v2s(nbtb[j]));
        const v2f ezA = v2exp2(zA);
        const v2f ezB = v2exp2(zB);

        const v2f aA = vfma(exA * exA, 2.7182818284590452f, v2s(1.0f));
        const v2f aB = vfma(exB * exB, 2.7182818284590452f, v2s(1.0f));
        const v2f bA = exA + 1.0f;
        const v2f bB = exB + 1.0f;
        const v2f rabA = v2rcp(aA * bA);
        const v2f rabB = v2rcp(aB * bB);
        const v2f ttA = v2rcp(ezA + 1.0f);
        const v2f ttB = v2rcp(ezB + 1.0f);

        const v2f xA = x2A * LN2;
        const v2f xB = x2B * LN2;
        const v2f t1A = vfma(bA * rabA, -2.0f, v2s(1.0f));
        const v2f t1B = vfma(bB * rabB, -2.0f, v2s(1.0f));
        const v2f t2A = vfma(aA * rabA,  2.0f, v2s(-1.0f));
        const v2f t2B = vfma(aB * rabB,  2.0f, v2s(-1.0f));

        const v2f m1A = vfma(-t1A, t1A, v2s(1.0f));
        const v2f m1B = vfma(-t1B, t1B, v2s(1.0f));
        const v2f m2A = vfma(-t2A, t2A, v2s(1.0f));
        const v2f m2B = vfma(-t2B, t2B, v2s(1.0f));
        const v2f uA  = vfma(xA, t1A, t2A + 5.0e-4f);
        const v2f uB  = vfma(xB, t1B, t2B + 5.0e-4f);
        const v2f rA  = v2rsq(uA);
        const v2f rB  = v2rsq(uB);

        const v2f xm1A = xA * m1A;
        const v2f xm1B = xB * m1B;
        const v2f uxA  = vfma(m2A, -0.5f, t1A + xm1A);
        const v2f uxB  = vfma(m2B, -0.5f, t1B + xm1B);
        const v2f f1A  = vfma(-t1A, xm1A, m1A);
        const v2f f1B  = vfma(-t1B, xm1B, m1B);
        // uxx2 = 2*uxx = 4*f1 - t2*m2
        const v2f uxx2A = vfma(f1A, 4.0f, -(t2A * m2A));
        const v2f uxx2B = vfma(f1B, 4.0f, -(t2B * m2B));

        const v2f tlA = uA * rA;                         // sqrt(u)
        const v2f tlB = uB * rB;
        const v2f ruA = rA * rA;                         // 1/u
        const v2f ruB = rB * rB;
        const v2f hhA = uxA * ruA;                       // ux/u
        const v2f hhB = uxB * ruB;
        // inner2 = 2*uxx - ux^2/u
        const v2f inner2A = vfma(-uxA, hhA, uxx2A);
        const v2f inner2B = vfma(-uxB, hhB, uxx2B);

        const v2f dttA = vfma(-ttA, ttA, ttA);
        const v2f dttB = vfma(-ttB, ttB, ttB);
        const v2f AAa  = ttA * ewe[j];
        const v2f AAb  = ttB * ewe[j];
        const v2f AAhA = AAa * hewl[j];                  // 0.5*ewl*AA
        const v2f AAhB = AAb * hewl[j];
        const v2f AAqA = AAa * qe2[j];                   // 0.25*ewl^2*AA
        const v2f AAqB = AAb * qe2[j];

        sa  = vfma(tlA, AAa, sa);
        sb  = vfma(tlB, AAb, sb);
        sLa = vfma(uxA * rA, AAhA, sLa);
        sLb = vfma(uxB * rB, AAhB, sLb);
        sLLa = vfma(inner2A * rA, AAqA, sLLa);
        sLLb = vfma(inner2B * rB, AAqB, sLLb);
        sTa = vfma(tlA * dttA, wte[j], sTa);
        sTb = vfma(tlB * dttB, wte[j], sTb);
    }

    // ============ phase 2: LUT eval of {o, o', o''}(s) for 4 samples ============
    float F0[4], F1[4], F2[4];
    lut_eval(lut, sa.x, F0[0], F1[0], F2[0]);
    lut_eval(lut, sa.y, F0[1], F1[1], F2[1]);
    lut_eval(lut, sb.x, F0[2], F1[2], F2[2]);
    lut_eval(lut, sb.y, F0[3], F1[3], F2[3]);

    const size_t nn = (size_t)n;
    ((float4*)(out))[tid] = make_float4(F0[0], F0[1], F0[2], F0[3]);
    ((float4*)(out + nn))[tid] =
        make_float4(sTa.x * F1[0], sTa.y * F1[1], sTb.x * F1[2], sTb.y * F1[3]);
    ((float4*)(out + 2 * nn))[tid] =
        make_float4(sLa.x * F1[0], sLa.y * F1[1], sLb.x * F1[2], sLb.y * F1[3]);
    ((float4*)(out + 3 * nn))[tid] = make_float4(
        fmaf(sLa.x * sLa.x, F2[0], sLLa.x * F1[0]),
        fmaf(sLa.y * sLa.y, F2[1], sLLa.y * F1[1]),
        fmaf(sLb.x * sLb.x, F2[2], sLLb.x * F1[2]),
        fmaf(sLb.y * sLb.y, F2[3], sLLb.y * F1[3]));
}

extern "C" void kernel_launch(void* const* d_in, const int* in_sizes, int n_in,
                              void* d_out, int out_size, void* d_ws, size_t ws_size,
                              hipStream_t stream) {
    const float* ttm    = (const float*)d_in[0];
    const float* logm   = (const float*)d_in[1];
    const float* w_logm = (const float*)d_in[2];
    const float* b_logm = (const float*)d_in[3];
    const float* w_ttm  = (const float*)d_in[4];
    const float* b_ttm  = (const float*)d_in[5];
    const float* w_exp  = (const float*)d_in[6];
    const float* b_exp  = (const float*)d_in[7];
    const float* W1     = (const float*)d_in[8];
    const float* b1     = (const float*)d_in[9];
    const float* W2     = (const float*)d_in[10];
    const float* b2     = (const float*)d_in[11];
    const float* Wo     = (const float*)d_in[12];
    const float* bo     = (const float*)d_in[13];
    float* out = (float*)d_out;
    float* cns = (float*)d_ws;   // 1536 + 45 floats ≈ 6.3 KB

    const int n = in_sizes[0];
    setup_kernel<<<1, NSEG, 0, stream>>>(w_logm, b_logm, w_ttm, b_ttm, w_exp, b_exp,
                                         W1, b1, W2, b2, Wo, bo, cns);
    const int threads = (n + 3) / 4;
    const int blocks  = (threads + 255) / 256;
    smile_main<<<blocks, 256, 0, stream>>>(ttm, logm, cns, out, n);
}